// Round 3
// baseline (50.252 us; speedup 1.0000x reference)
//
#include <hip/hip_runtime.h>

typedef float f32x2 __attribute__((ext_vector_type(2)));
typedef float f32x4 __attribute__((ext_vector_type(4)));

#define TPB 256
#define RQ 8                  // query points per thread
#define QTILE (TPB * RQ)      // 2048 queries per block
#define TTILE 256             // targets staged in LDS per block
#define NPAIR (TTILE / 2)     // target pairs
#define OFFSET 128.0f         // keeps accumulated f' = 128 + d - ||q||^2 > 0

// Single-instruction 3-way min: avoids llvm.minnum's sNaN canonicalization
// (v_max x,x) that tripled the min cost in R2. Inputs are never NaN here.
__device__ __forceinline__ float min3(float a, float b, float c) {
    float d;
    asm("v_min3_f32 %0, %1, %2, %3" : "=v"(d) : "v"(a), "v"(b), "v"(c));
    return d;
}

__device__ __forceinline__ f32x2 pk_fma(f32x2 a, f32x2 b, f32x2 c) {
#if __has_builtin(__builtin_elementwise_fma)
    return __builtin_elementwise_fma(a, b, c);   // -> v_pk_fma_f32
#else
    f32x2 d;
    d.x = __builtin_fmaf(a.x, b.x, c.x);
    d.y = __builtin_fmaf(a.y, b.y, c.y);
    return d;
#endif
}

// blockIdx.z = b*2 + dir. dir==0: queries=xyz1, targets=xyz2 (dist1); dir==1 swapped.
// d_out accumulates f' = min_t (128 + ||t||^2 - 2 q.t) as uint bits via atomicMin.
__global__ void __launch_bounds__(TPB) cd_main(
        const float* __restrict__ xyz1, const float* __restrict__ xyz2,
        unsigned int* __restrict__ out, int B, int N, int M) {
    __shared__ f32x4 ldsA[NPAIR];  // (x0, x1, y0, y1)
    __shared__ f32x4 ldsB[NPAIR];  // (z0, z1, w0, w1)

    const int zi  = blockIdx.z;
    const int b   = zi >> 1;
    const int dir = zi & 1;

    const float* q = dir ? (xyz2 + (size_t)b * M * 3) : (xyz1 + (size_t)b * N * 3);
    const float* t = dir ? (xyz1 + (size_t)b * N * 3) : (xyz2 + (size_t)b * M * 3);
    unsigned int* o = out + (dir ? ((size_t)B * N + (size_t)b * M) : ((size_t)b * N));

    // Stage target tile in paired layout. Threads 0..NPAIR-1 each own one pair.
    if (threadIdx.x < NPAIR) {
        const float* tp = t + ((size_t)blockIdx.x * TTILE + 2 * threadIdx.x) * 3;
        float x0 = tp[0], y0 = tp[1], z0 = tp[2];
        float x1 = tp[3], y1 = tp[4], z1 = tp[5];
        float w0 = OFFSET + __builtin_fmaf(x0, x0, __builtin_fmaf(y0, y0, z0 * z0));
        float w1 = OFFSET + __builtin_fmaf(x1, x1, __builtin_fmaf(y1, y1, z1 * z1));
        ldsA[threadIdx.x] = (f32x4){x0, x1, y0, y1};
        ldsB[threadIdx.x] = (f32x4){z0, z1, w0, w1};
    }
    __syncthreads();

    // Per-thread queries, m = -2q broadcast into both packed halves.
    const int q0 = blockIdx.y * QTILE + threadIdx.x;
    f32x2 mx[RQ], my[RQ], mz[RQ];
    float best[RQ];
    #pragma unroll
    for (int r = 0; r < RQ; ++r) {
        const float* qp = q + (size_t)(q0 + r * TPB) * 3;
        float a = -2.0f * qp[0], bq = -2.0f * qp[1], c = -2.0f * qp[2];
        mx[r] = (f32x2){a, a};
        my[r] = (f32x2){bq, bq};
        mz[r] = (f32x2){c, c};
        best[r] = 3.402823466e+38f;
    }

    // Per 2 targets x query: 3 v_pk_fma_f32 + 1 v_min3_f32 = 2 issue slots/pair.
    // All lanes read the same LDS address -> broadcast, conflict-free.
    #pragma unroll 4
    for (int j = 0; j < NPAIR; ++j) {
        f32x4 A = ldsA[j];
        f32x4 Bv = ldsB[j];
        f32x2 x01 = (f32x2){A.x, A.y};
        f32x2 y01 = (f32x2){A.z, A.w};
        f32x2 z01 = (f32x2){Bv.x, Bv.y};
        f32x2 w01 = (f32x2){Bv.z, Bv.w};
        #pragma unroll
        for (int r = 0; r < RQ; ++r) {
            f32x2 acc = pk_fma(z01, mz[r], w01);
            acc = pk_fma(y01, my[r], acc);
            acc = pk_fma(x01, mx[r], acc);
            best[r] = min3(acc.x, acc.y, best[r]);
        }
    }

    // f' > 0 guaranteed by OFFSET -> IEEE order == uint order.
    #pragma unroll
    for (int r = 0; r < RQ; ++r)
        atomicMin(o + (q0 + r * TPB), __float_as_uint(best[r]));
}

// In-place: out[i] = f' - 128 + ||q_i||^2
__global__ void cd_finalize(const float* __restrict__ xyz1, const float* __restrict__ xyz2,
                            float* __restrict__ out, int B, int N, int M) {
    int i = blockIdx.x * TPB + threadIdx.x;
    int total = B * N + B * M;
    if (i >= total) return;
    const float* qp;
    if (i < B * N) {
        qp = xyz1 + (size_t)i * 3;
    } else {
        qp = xyz2 + (size_t)(i - B * N) * 3;
    }
    float f  = __uint_as_float(((const unsigned int*)out)[i]);
    float sq = __builtin_fmaf(qp[0], qp[0],
               __builtin_fmaf(qp[1], qp[1], qp[2] * qp[2]));
    out[i] = f - OFFSET + sq;
}

extern "C" void kernel_launch(void* const* d_in, const int* in_sizes, int n_in,
                              void* d_out, int out_size, void* d_ws, size_t ws_size,
                              hipStream_t stream) {
    const float* xyz1 = (const float*)d_in[0];
    const float* xyz2 = (const float*)d_in[1];

    const int B = 4, N = 8192, M = 8192;

    // 0x7F7F7F7F == 3.39e38f: valid huge float, upper bound for bits-atomicMin.
    hipMemsetAsync(d_out, 0x7F, (size_t)out_size * sizeof(float), stream);

    // grid.x: target tiles (32), grid.y: query tiles (4), grid.z: batch*dir (8)
    dim3 grid(M / TTILE, N / QTILE, B * 2);
    cd_main<<<grid, TPB, 0, stream>>>(xyz1, xyz2, (unsigned int*)d_out, B, N, M);

    cd_finalize<<<dim3((out_size + TPB - 1) / TPB), TPB, 0, stream>>>(
        xyz1, xyz2, (float*)d_out, B, N, M);
}

// Round 4
// 34.760 us; speedup vs baseline: 1.4457x; 1.4457x over previous
//
#include <hip/hip_runtime.h>

typedef _Float16 half8 __attribute__((ext_vector_type(8)));
typedef float f32x16 __attribute__((ext_vector_type(16)));

#define NQ 4   // query groups (of 32) per wave

__device__ __forceinline__ float min3f(float a, float b, float c) {
    float d;
    asm("v_min3_f32 %0, %1, %2, %3" : "=v"(d) : "v"(a), "v"(b), "v"(c));
    return d;
}

// ---------------- prep: target A-fragment arrays for all 8 (dir,b) ----------------
// frag layout: half8 [8 bd][256 group][64 lane]. Lane l holds k-slots (l>>5)*8+e of
// target row (l&31). K-slot table (A/target):
//  k: 0:xh 1:xh 2:xl 3:yh 4:yh 5:yl 6:zh 7:zh 8:zl 9:sqh 10:sql 11:1 12:1 13-15:0
// (any consistent (half,e)->k map is valid: MFMA dot product is K-permutation-invariant
//  as long as A and B use the same map)
__global__ void cd_prep(const float* __restrict__ xyz1,
                        const float* __restrict__ xyz2,
                        _Float16* __restrict__ frag) {
    int tid  = blockIdx.x * 256 + threadIdx.x;   // 131072 threads
    int aidx = tid >> 14;                        // bd = dir*4+b
    int rem  = tid & 16383;
    int g = rem >> 6, l = rem & 63;
    int dir = aidx >> 2, b = aidx & 3;
    const float* src = (dir ? xyz1 : xyz2) + (size_t)b * 8192 * 3;
    int t = g * 32 + (l & 31);
    float x = src[t*3+0], y = src[t*3+1], z = src[t*3+2];
    float sq = __builtin_fmaf(x, x, __builtin_fmaf(y, y, z * z));
    _Float16 xh = (_Float16)x, yh = (_Float16)y, zh = (_Float16)z;
    _Float16 xl = (_Float16)(x - (float)xh);
    _Float16 yl = (_Float16)(y - (float)yh);
    _Float16 zl = (_Float16)(z - (float)zh);
    _Float16 sh = (_Float16)sq;
    _Float16 sl = (_Float16)(sq - (float)sh);
    const _Float16 one = (_Float16)1.0f, zero = (_Float16)0.0f;
    half8 f;
    if ((l >> 5) == 0) {
        f[0]=xh; f[1]=xh; f[2]=xl; f[3]=yh; f[4]=yh; f[5]=yl; f[6]=zh; f[7]=zh;
    } else {
        f[0]=zl; f[1]=sh; f[2]=sl; f[3]=one; f[4]=one; f[5]=zero; f[6]=zero; f[7]=zero;
    }
    ((half8*)frag)[(size_t)aidx * 16384 + g * 64 + l] = f;
}

// ---------------- main ----------------
// block: 4 waves, 128 queries (shared), each wave scans a 2048-target quarter.
// S = |t|^2 + |q|^2 - 2 q.t  computed entirely inside the MFMA via K-slot packing.
#define FOLD(Dv, bj)                                   \
    bj = min3f(Dv[0],  Dv[1],  bj);                    \
    bj = min3f(Dv[2],  Dv[3],  bj);                    \
    bj = min3f(Dv[4],  Dv[5],  bj);                    \
    bj = min3f(Dv[6],  Dv[7],  bj);                    \
    bj = min3f(Dv[8],  Dv[9],  bj);                    \
    bj = min3f(Dv[10], Dv[11], bj);                    \
    bj = min3f(Dv[12], Dv[13], bj);                    \
    bj = min3f(Dv[14], Dv[15], bj);

__global__ void __launch_bounds__(256) cd_main(
        const float* __restrict__ xyz1, const float* __restrict__ xyz2,
        const _Float16* __restrict__ frag, float* __restrict__ out) {
    __shared__ float red[4][128];
    const int qt  = blockIdx.x;          // 64 query tiles of 128
    const int bd  = blockIdx.y;          // dir*4 + b
    const int dir = bd >> 2, b = bd & 3;
    const int l = threadIdx.x & 63, w = threadIdx.x >> 6;
    const int h = l >> 5;
    const float* q = (dir ? xyz2 : xyz1) + (size_t)b * 8192 * 3;
    const int qbase = qt * 128;

    // B-fragments (queries), built once. K-slot table (B/query):
    //  k: 0:mxh 1:mxl 2:mxh 3:myh 4:myl 5:myh 6:mzh 7:mzl 8:mzh 9:1 10:1 11:sqh 12:sql 13-15:0
    half8 Bf[NQ];
    const _Float16 one = (_Float16)1.0f, zero = (_Float16)0.0f;
    #pragma unroll
    for (int j = 0; j < NQ; ++j) {
        int qi = qbase + j * 32 + (l & 31);
        float px = q[qi*3+0], py = q[qi*3+1], pz = q[qi*3+2];
        float mx = -2.f * px, my = -2.f * py, mz = -2.f * pz;
        float sq = __builtin_fmaf(px, px, __builtin_fmaf(py, py, pz * pz));
        _Float16 mxh = (_Float16)mx, mxl = (_Float16)(mx - (float)mxh);
        _Float16 myh = (_Float16)my, myl = (_Float16)(my - (float)myh);
        _Float16 mzh = (_Float16)mz, mzl = (_Float16)(mz - (float)mzh);
        _Float16 sh  = (_Float16)sq, sl  = (_Float16)(sq - (float)sh);
        half8 f;
        if (h == 0) { f[0]=mxh; f[1]=mxl; f[2]=mxh; f[3]=myh; f[4]=myl; f[5]=myh; f[6]=mzh; f[7]=mzl; }
        else        { f[0]=mzh; f[1]=one; f[2]=one; f[3]=sh; f[4]=sl; f[5]=zero; f[6]=zero; f[7]=zero; }
        Bf[j] = f;
    }

    f32x16 Z;
    #pragma unroll
    for (int i = 0; i < 16; ++i) Z[i] = 0.f;

    float best[NQ];
    #pragma unroll
    for (int j = 0; j < NQ; ++j) best[j] = 3.0e38f;

    // wave w's target quarter: groups w*64 .. w*64+63; one dwordx4 per group per lane.
    const half8* Ap = ((const half8*)frag) + (size_t)bd * 16384 + w * 4096 + l;

    half8 a = Ap[0];
    #pragma unroll 2
    for (int g = 0; g < 63; ++g) {
        half8 an = Ap[(size_t)(g + 1) * 64];   // prefetch next group
        #pragma unroll
        for (int j = 0; j < NQ; ++j) {
            f32x16 D = __builtin_amdgcn_mfma_f32_32x32x16_f16(a, Bf[j], Z, 0, 0, 0);
            FOLD(D, best[j]);
        }
        a = an;
    }
    #pragma unroll
    for (int j = 0; j < NQ; ++j) {
        f32x16 D = __builtin_amdgcn_mfma_f32_32x32x16_f16(a, Bf[j], Z, 0, 0, 0);
        FOLD(D, best[j]);
    }

    // C/D: col = lane&31 (HW-verified); lane halves cover disjoint target rows.
    #pragma unroll
    for (int j = 0; j < NQ; ++j) {
        float o = __shfl_xor(best[j], 32, 64);
        best[j] = fminf(best[j], o);
    }
    if (l < 32) {
        #pragma unroll
        for (int j = 0; j < NQ; ++j) red[w][j * 32 + l] = best[j];
    }
    __syncthreads();
    if (threadIdx.x < 128) {
        int t = threadIdx.x;
        float m = fminf(fminf(red[0][t], red[1][t]), fminf(red[2][t], red[3][t]));
        out[(size_t)dir * 32768 + (size_t)b * 8192 + qbase + t] = m;
    }
}

extern "C" void kernel_launch(void* const* d_in, const int* in_sizes, int n_in,
                              void* d_out, int out_size, void* d_ws, size_t ws_size,
                              hipStream_t stream) {
    const float* xyz1 = (const float*)d_in[0];
    const float* xyz2 = (const float*)d_in[1];
    _Float16* frag = (_Float16*)d_ws;   // needs 2 MB of scratch

    cd_prep<<<512, 256, 0, stream>>>(xyz1, xyz2, frag);

    dim3 grid(64, 8);                   // 64 query tiles x (dir*4+b)
    cd_main<<<grid, 256, 0, stream>>>(xyz1, xyz2, frag, (float*)d_out);
}